// Round 1
// baseline (640.739 us; speedup 1.0000x reference)
//
#include <hip/hip_runtime.h>
#include <hip/hip_bf16.h>
#include <math.h>

// Problem constants
#define B_  8
#define T_  2048
#define C_  768
#define HS_ 256

typedef float  f32x4  __attribute__((ext_vector_type(4)));
typedef __bf16 bf16x8 __attribute__((ext_vector_type(8)));
typedef __bf16 bf16x4 __attribute__((ext_vector_type(4)));

#define MFMA16(a, b, c) __builtin_amdgcn_mfma_f32_16x16x32_bf16((a), (b), (c), 0, 0, 0)

// ---------------------------------------------------------------------------
// Kernel 1: transpose + convert weights to bf16.
//   W  : [768][256] fp32 (k-major, as stored: x @ W)
//   Wt : [256][768] bf16 (n-major) so MFMA B-fragments read contiguous k.
// Softmax scale * log2(e) folded into Wq.
// ---------------------------------------------------------------------------
__global__ __launch_bounds__(256) void wt_kernel(const float* __restrict__ Wq,
                                                 const float* __restrict__ Wk,
                                                 const float* __restrict__ Wv,
                                                 __bf16* __restrict__ wt_all,
                                                 float qscale) {
    int idx = blockIdx.x * 256 + threadIdx.x;   // [0, 768*256)
    int mat = blockIdx.y;
    const float* W = (mat == 0) ? Wq : ((mat == 1) ? Wk : Wv);
    float scale = (mat == 0) ? qscale : 1.0f;
    int k = idx >> 8;    // 0..767
    int n = idx & 255;   // 0..255
    wt_all[(size_t)mat * (HS_ * C_) + n * C_ + k] = (__bf16)(W[idx] * scale);
}

// ---------------------------------------------------------------------------
// Kernel 2: projection GEMM  Y = X @ W  (one matrix per blockIdx.y)
//   X [16384][768] fp32, Wt [256][768] bf16 -> Y [16384][256] bf16
//   mat 0 -> qb (row-major), 1 -> kb (row-major), 2 -> vt TRANSPOSED [b][d][t]
// Block: 256 thr (4 waves); wave w computes rows [m0+16w, m0+16w+16) x 256.
// ---------------------------------------------------------------------------
__global__ __launch_bounds__(256) void proj_kernel(const float* __restrict__ x,
                                                   const __bf16* __restrict__ wt_all,
                                                   __bf16* __restrict__ qb,
                                                   __bf16* __restrict__ kb,
                                                   __bf16* __restrict__ vt) {
    const int tid  = threadIdx.x;
    const int w    = tid >> 6;
    const int lane = tid & 63;
    const int cm   = lane & 15;   // MFMA m / n index
    const int quad = lane >> 4;   // MFMA k-group
    const int m0   = blockIdx.x * 64;
    const int mat  = blockIdx.y;
    const __bf16* wt = wt_all + (size_t)mat * (HS_ * C_);

    const int r = m0 + w * 16 + cm;           // global X row for A-fragment
    f32x4 acc[16];
#pragma unroll
    for (int i = 0; i < 16; i++) acc[i] = (f32x4){0.f, 0.f, 0.f, 0.f};

    const float* xp = x + (size_t)r * C_ + quad * 8;

    for (int ks = 0; ks < C_ / 32; ks++) {    // 24 k-steps of 32
        // A-fragment: 8 consecutive fp32 -> bf16
        f32x4 xa = *(const f32x4*)(xp + ks * 32);
        f32x4 xb = *(const f32x4*)(xp + ks * 32 + 4);
        bf16x8 af;
        af[0] = (__bf16)xa[0]; af[1] = (__bf16)xa[1];
        af[2] = (__bf16)xa[2]; af[3] = (__bf16)xa[3];
        af[4] = (__bf16)xb[0]; af[5] = (__bf16)xb[1];
        af[6] = (__bf16)xb[2]; af[7] = (__bf16)xb[3];
#pragma unroll
        for (int nt = 0; nt < 16; nt++) {
            bf16x8 bf = *(const bf16x8*)(wt + (nt * 16 + cm) * C_ + ks * 32 + quad * 8);
            acc[nt] = MFMA16(af, bf, acc[nt]);
        }
    }

    // Epilogue. C/D layout: col = lane&15 (=cm), row = quad*4 + reg.
    const int rb = m0 + w * 16 + quad * 4;
    if (mat < 2) {
        __bf16* out = (mat == 0) ? qb : kb;
#pragma unroll
        for (int nt = 0; nt < 16; nt++)
#pragma unroll
            for (int i = 0; i < 4; i++)
                out[(size_t)(rb + i) * HS_ + nt * 16 + cm] = (__bf16)acc[nt][i];
    } else {
        // vt[b][d][t]: 4 regs are 4 consecutive t -> one 8B store each
        const int bb = rb >> 11;        // row / 2048
        const int t  = rb & 2047;
#pragma unroll
        for (int nt = 0; nt < 16; nt++) {
            bf16x4 v4;
            v4[0] = (__bf16)acc[nt][0]; v4[1] = (__bf16)acc[nt][1];
            v4[2] = (__bf16)acc[nt][2]; v4[3] = (__bf16)acc[nt][3];
            *(bf16x4*)(vt + (size_t)bb * (HS_ * T_) + (nt * 16 + cm) * T_ + t) = v4;
        }
    }
}

// ---------------------------------------------------------------------------
// Kernel 3: causal flash attention.
//   One block per (batch, 64-row q tile); 4 waves, wave = 16 q rows.
//   Q frags in registers; K/V frags direct from global (L2);
//   P goes through per-wave LDS in A-fragment order.
//   exp2-domain softmax (scale*log2e folded into Wq).
// ---------------------------------------------------------------------------
__global__ __launch_bounds__(256) void flash_kernel(const __bf16* __restrict__ qb,
                                                    const __bf16* __restrict__ kb,
                                                    const __bf16* __restrict__ vt,
                                                    float* __restrict__ out) {
    // P buffer per wave, A-fragment order: [wave][kstep2][quad][m][j]
    __shared__ __bf16 ldsP[4][2][4][16][8];

    const int tid  = threadIdx.x;
    const int w    = tid >> 6;
    const int lane = tid & 63;
    const int cm   = lane & 15;
    const int quad = lane >> 4;
    const int b    = blockIdx.x >> 5;
    const int qblk = blockIdx.x & 31;

    const int qrow = qblk * 64 + w * 16 + cm;           // within batch
    const __bf16* qp = qb + ((size_t)b * T_ + qrow) * HS_ + quad * 8;
    bf16x8 qf[8];
#pragma unroll
    for (int ks = 0; ks < 8; ks++) qf[ks] = *(const bf16x8*)(qp + ks * 32);

    f32x4 accO[16];
#pragma unroll
    for (int i = 0; i < 16; i++) accO[i] = (f32x4){0.f, 0.f, 0.f, 0.f};
    float mi[4], li[4];
#pragma unroll
    for (int i = 0; i < 4; i++) { mi[i] = -__builtin_inff(); li[i] = 0.f; }

    const int qg = qblk * 64 + w * 16 + quad * 4;       // q row of acc reg i is qg+i

    for (int kt = 0; kt <= qblk; kt++) {
        // ---- S = Q K^T (16 x 64 per wave) ----
        f32x4 s[4];
#pragma unroll
        for (int i = 0; i < 4; i++) s[i] = (f32x4){0.f, 0.f, 0.f, 0.f};
        const __bf16* kp = kb + ((size_t)b * T_ + kt * 64) * HS_;
#pragma unroll
        for (int nsub = 0; nsub < 4; nsub++) {
            const __bf16* kr = kp + (nsub * 16 + cm) * HS_ + quad * 8;
#pragma unroll
            for (int ks = 0; ks < 8; ks++) {
                bf16x8 kf = *(const bf16x8*)(kr + ks * 32);
                s[nsub] = MFMA16(qf[ks], kf, s[nsub]);
            }
        }
        // ---- causal mask (diagonal tile only) ----
        if (kt == qblk) {
#pragma unroll
            for (int nsub = 0; nsub < 4; nsub++)
#pragma unroll
                for (int i = 0; i < 4; i++)
                    if (kt * 64 + nsub * 16 + cm > qg + i)
                        s[nsub][i] = -__builtin_inff();
        }
        // ---- online softmax (rows live in 16-lane quads) ----
        float pm[4];
#pragma unroll
        for (int i = 0; i < 4; i++)
            pm[i] = fmaxf(fmaxf(s[0][i], s[1][i]), fmaxf(s[2][i], s[3][i]));
#pragma unroll
        for (int off = 1; off < 16; off <<= 1)
#pragma unroll
            for (int i = 0; i < 4; i++)
                pm[i] = fmaxf(pm[i], __shfl_xor(pm[i], off));

        float alpha[4], rs[4];
#pragma unroll
        for (int i = 0; i < 4; i++) {
            float mn = fmaxf(mi[i], pm[i]);
            alpha[i] = exp2f(mi[i] - mn);
            mi[i] = mn;
            rs[i] = 0.f;
        }
        // p = exp2(s - m); write to LDS in A-fragment order
#pragma unroll
        for (int nsub = 0; nsub < 4; nsub++)
#pragma unroll
            for (int i = 0; i < 4; i++) {
                float p = exp2f(s[nsub][i] - mi[i]);
                rs[i] += p;
                int c = nsub * 16 + cm;
                ldsP[w][c >> 5][(c >> 3) & 3][quad * 4 + i][c & 7] = (__bf16)p;
            }
#pragma unroll
        for (int off = 1; off < 16; off <<= 1)
#pragma unroll
            for (int i = 0; i < 4; i++)
                rs[i] += __shfl_xor(rs[i], off);
#pragma unroll
        for (int i = 0; i < 4; i++) li[i] = li[i] * alpha[i] + rs[i];
#pragma unroll
        for (int nt = 0; nt < 16; nt++)
#pragma unroll
            for (int i = 0; i < 4; i++) accO[nt][i] *= alpha[i];

        __syncthreads();   // P writes visible before fragment reads
        // ---- O += P V ----
        const __bf16* vp = vt + (size_t)b * (HS_ * T_) + kt * 64;
#pragma unroll
        for (int ks2 = 0; ks2 < 2; ks2++) {
            bf16x8 pf = *(const bf16x8*)&ldsP[w][ks2][quad][cm][0];
            const __bf16* vr = vp + ks2 * 32 + quad * 8;
#pragma unroll
            for (int nt = 0; nt < 16; nt++) {
                bf16x8 vf = *(const bf16x8*)(vr + (nt * 16 + cm) * T_);
                accO[nt] = MFMA16(pf, vf, accO[nt]);
            }
        }
        __syncthreads();   // P reads done before next iteration's writes
    }

    // ---- epilogue: normalize and store fp32 ----
    float inv[4];
#pragma unroll
    for (int i = 0; i < 4; i++) inv[i] = 1.0f / li[i];
    const int orow = b * T_ + qblk * 64 + w * 16 + quad * 4;
#pragma unroll
    for (int nt = 0; nt < 16; nt++)
#pragma unroll
        for (int i = 0; i < 4; i++)
            out[(size_t)(orow + i) * HS_ + nt * 16 + cm] = accO[nt][i] * inv[i];
}

// ---------------------------------------------------------------------------
extern "C" void kernel_launch(void* const* d_in, const int* in_sizes, int n_in,
                              void* d_out, int out_size, void* d_ws, size_t ws_size,
                              hipStream_t stream) {
    const float* x  = (const float*)d_in[0];
    const float* Wq = (const float*)d_in[1];
    const float* Wk = (const float*)d_in[2];
    const float* Wv = (const float*)d_in[3];
    float* out = (float*)d_out;

    char* ws = (char*)d_ws;
    // ws layout (bytes):
    //   wt_all : 3*256*768*2       = 1,179,648
    //   qb     : 8*2048*256*2      = 8,388,608
    //   kb     : 8,388,608
    //   vt     : 8,388,608   (transposed [b][d][t])
    __bf16* wt_all = (__bf16*)ws;
    __bf16* qbuf   = (__bf16*)(ws + 1179648);
    __bf16* kbuf   = (__bf16*)(ws + 1179648 + 8388608);
    __bf16* vbuf   = (__bf16*)(ws + 1179648 + 2 * 8388608);

    // softmax scale (note: C^-0.5, not HS^-0.5) in exp2 domain
    float qscale = 1.4426950408889634f / sqrtf((float)C_);

    wt_kernel<<<dim3(768, 3), 256, 0, stream>>>(Wq, Wk, Wv, wt_all, qscale);
    proj_kernel<<<dim3(256, 3), 256, 0, stream>>>(x, wt_all, qbuf, kbuf, vbuf);
    flash_kernel<<<dim3(256), 256, 0, stream>>>(qbuf, kbuf, vbuf, out);
}

// Round 2
// 481.794 us; speedup vs baseline: 1.3299x; 1.3299x over previous
//
#include <hip/hip_runtime.h>
#include <hip/hip_bf16.h>
#include <math.h>

// Problem constants
#define B_  8
#define T_  2048
#define C_  768
#define HS_ 256

// Split-K flash: chunk = 8 k-tiles (512 keys). Chunks per q-tile q: (q>>3)+1.
// Per batch: 8*1+8*2+8*3+8*4 = 80 chunks; total 640 partial blocks.
#define CHUNK_TILES 8
#define CHUNKS_PER_BATCH 80
#define NPART (CHUNKS_PER_BATCH * B_)   // 640

typedef float  f32x4  __attribute__((ext_vector_type(4)));
typedef __bf16 bf16x8 __attribute__((ext_vector_type(8)));
typedef __bf16 bf16x4 __attribute__((ext_vector_type(4)));

#define MFMA16(a, b, c) __builtin_amdgcn_mfma_f32_16x16x32_bf16((a), (b), (c), 0, 0, 0)

// cumulative chunk count before q-tile q (within a batch)
__device__ __forceinline__ int chunk_cum(int q) {
    int g = q >> 3;
    return 4 * g * (g + 1) + (q - 8 * g) * (g + 1);
}

// ---------------------------------------------------------------------------
// Kernel 1: transpose + convert weights to bf16.  Wq gets softmax scale *
// log2(e) folded in (exp2-domain softmax downstream).
// ---------------------------------------------------------------------------
__global__ __launch_bounds__(256) void wt_kernel(const float* __restrict__ Wq,
                                                 const float* __restrict__ Wk,
                                                 const float* __restrict__ Wv,
                                                 __bf16* __restrict__ wt_all,
                                                 float qscale) {
    int idx = blockIdx.x * 256 + threadIdx.x;   // [0, 768*256)
    int mat = blockIdx.y;
    const float* W = (mat == 0) ? Wq : ((mat == 1) ? Wk : Wv);
    float scale = (mat == 0) ? qscale : 1.0f;
    int k = idx >> 8;    // 0..767
    int n = idx & 255;   // 0..255
    wt_all[(size_t)mat * (HS_ * C_) + n * C_ + k] = (__bf16)(W[idx] * scale);
}

// ---------------------------------------------------------------------------
// Kernel 2: projection GEMM  Y = X @ W  (one matrix per blockIdx.y)
//   mat 0 -> qb (row-major), 1 -> kb (row-major), 2 -> vt TRANSPOSED [b][d][t]
// ---------------------------------------------------------------------------
__global__ __launch_bounds__(256) void proj_kernel(const float* __restrict__ x,
                                                   const __bf16* __restrict__ wt_all,
                                                   __bf16* __restrict__ qb,
                                                   __bf16* __restrict__ kb,
                                                   __bf16* __restrict__ vt) {
    const int tid  = threadIdx.x;
    const int w    = tid >> 6;
    const int lane = tid & 63;
    const int cm   = lane & 15;
    const int quad = lane >> 4;
    const int m0   = blockIdx.x * 64;
    const int mat  = blockIdx.y;
    const __bf16* wt = wt_all + (size_t)mat * (HS_ * C_);

    const int r = m0 + w * 16 + cm;
    f32x4 acc[16];
#pragma unroll
    for (int i = 0; i < 16; i++) acc[i] = (f32x4){0.f, 0.f, 0.f, 0.f};

    const float* xp = x + (size_t)r * C_ + quad * 8;

    for (int ks = 0; ks < C_ / 32; ks++) {
        f32x4 xa = *(const f32x4*)(xp + ks * 32);
        f32x4 xb = *(const f32x4*)(xp + ks * 32 + 4);
        bf16x8 af;
        af[0] = (__bf16)xa[0]; af[1] = (__bf16)xa[1];
        af[2] = (__bf16)xa[2]; af[3] = (__bf16)xa[3];
        af[4] = (__bf16)xb[0]; af[5] = (__bf16)xb[1];
        af[6] = (__bf16)xb[2]; af[7] = (__bf16)xb[3];
#pragma unroll
        for (int nt = 0; nt < 16; nt++) {
            bf16x8 bf = *(const bf16x8*)(wt + (nt * 16 + cm) * C_ + ks * 32 + quad * 8);
            acc[nt] = MFMA16(af, bf, acc[nt]);
        }
    }

    const int rb = m0 + w * 16 + quad * 4;
    if (mat < 2) {
        __bf16* out = (mat == 0) ? qb : kb;
#pragma unroll
        for (int nt = 0; nt < 16; nt++)
#pragma unroll
            for (int i = 0; i < 4; i++)
                out[(size_t)(rb + i) * HS_ + nt * 16 + cm] = (__bf16)acc[nt][i];
    } else {
        const int bb = rb >> 11;
        const int t  = rb & 2047;
#pragma unroll
        for (int nt = 0; nt < 16; nt++) {
            bf16x4 v4;
            v4[0] = (__bf16)acc[nt][0]; v4[1] = (__bf16)acc[nt][1];
            v4[2] = (__bf16)acc[nt][2]; v4[3] = (__bf16)acc[nt][3];
            *(bf16x4*)(vt + (size_t)bb * (HS_ * T_) + (nt * 16 + cm) * T_ + t) = v4;
        }
    }
}

// ---------------------------------------------------------------------------
// Kernel 3a: split-K causal flash partial.
//   One block per (batch, q-tile, k-chunk). Writes unnormalized O (fp32),
//   row max m and row sum l to workspace. Every row in every chunk has at
//   least one unmasked key (chunk exists only if its first key <= row).
// ---------------------------------------------------------------------------
__global__ __launch_bounds__(256) void flash_part(const __bf16* __restrict__ qb,
                                                  const __bf16* __restrict__ kb,
                                                  const __bf16* __restrict__ vt,
                                                  float* __restrict__ Opart,
                                                  float* __restrict__ mpart,
                                                  float* __restrict__ lpart) {
    __shared__ __bf16 ldsP[4][2][4][16][8];

    const int tid  = threadIdx.x;
    const int w    = tid >> 6;
    const int lane = tid & 63;
    const int cm   = lane & 15;
    const int quad = lane >> 4;

    const int pid = blockIdx.x;                 // [0, 640)
    const int b   = pid / CHUNKS_PER_BATCH;
    int r = pid - b * CHUNKS_PER_BATCH;         // [0, 80)
    // decode (qblk, ci): group g has 8 q-tiles with (g+1) chunks each
    int qblk = 0, ci = 0;
#pragma unroll
    for (int g = 0; g < 4; g++) {
        int gs = 8 * (g + 1);
        if (r < gs) { qblk = g * 8 + r / (g + 1); ci = r % (g + 1); break; }
        r -= gs;
    }
    const int kt_begin = ci * CHUNK_TILES;
    const int kt_end   = min(kt_begin + CHUNK_TILES, qblk + 1);

    const int qrow = qblk * 64 + w * 16 + cm;
    const __bf16* qp = qb + ((size_t)b * T_ + qrow) * HS_ + quad * 8;
    bf16x8 qf[8];
#pragma unroll
    for (int ks = 0; ks < 8; ks++) qf[ks] = *(const bf16x8*)(qp + ks * 32);

    f32x4 accO[16];
#pragma unroll
    for (int i = 0; i < 16; i++) accO[i] = (f32x4){0.f, 0.f, 0.f, 0.f};
    float mi[4], li[4];
#pragma unroll
    for (int i = 0; i < 4; i++) { mi[i] = -__builtin_inff(); li[i] = 0.f; }

    const int qg = qblk * 64 + w * 16 + quad * 4;

    for (int kt = kt_begin; kt < kt_end; kt++) {
        f32x4 s[4];
#pragma unroll
        for (int i = 0; i < 4; i++) s[i] = (f32x4){0.f, 0.f, 0.f, 0.f};
        const __bf16* kp = kb + ((size_t)b * T_ + kt * 64) * HS_;
#pragma unroll
        for (int nsub = 0; nsub < 4; nsub++) {
            const __bf16* kr = kp + (nsub * 16 + cm) * HS_ + quad * 8;
#pragma unroll
            for (int ks = 0; ks < 8; ks++) {
                bf16x8 kf = *(const bf16x8*)(kr + ks * 32);
                s[nsub] = MFMA16(qf[ks], kf, s[nsub]);
            }
        }
        if (kt == qblk) {
#pragma unroll
            for (int nsub = 0; nsub < 4; nsub++)
#pragma unroll
                for (int i = 0; i < 4; i++)
                    if (kt * 64 + nsub * 16 + cm > qg + i)
                        s[nsub][i] = -__builtin_inff();
        }
        float pm[4];
#pragma unroll
        for (int i = 0; i < 4; i++)
            pm[i] = fmaxf(fmaxf(s[0][i], s[1][i]), fmaxf(s[2][i], s[3][i]));
#pragma unroll
        for (int off = 1; off < 16; off <<= 1)
#pragma unroll
            for (int i = 0; i < 4; i++)
                pm[i] = fmaxf(pm[i], __shfl_xor(pm[i], off));

        float alpha[4], rs[4];
#pragma unroll
        for (int i = 0; i < 4; i++) {
            float mn = fmaxf(mi[i], pm[i]);
            alpha[i] = exp2f(mi[i] - mn);
            mi[i] = mn;
            rs[i] = 0.f;
        }
#pragma unroll
        for (int nsub = 0; nsub < 4; nsub++)
#pragma unroll
            for (int i = 0; i < 4; i++) {
                float p = exp2f(s[nsub][i] - mi[i]);
                rs[i] += p;
                int c = nsub * 16 + cm;
                ldsP[w][c >> 5][(c >> 3) & 3][quad * 4 + i][c & 7] = (__bf16)p;
            }
#pragma unroll
        for (int off = 1; off < 16; off <<= 1)
#pragma unroll
            for (int i = 0; i < 4; i++)
                rs[i] += __shfl_xor(rs[i], off);
#pragma unroll
        for (int i = 0; i < 4; i++) li[i] = li[i] * alpha[i] + rs[i];
#pragma unroll
        for (int nt = 0; nt < 16; nt++)
#pragma unroll
            for (int i = 0; i < 4; i++) accO[nt][i] *= alpha[i];

        __syncthreads();
        const __bf16* vp = vt + (size_t)b * (HS_ * T_) + kt * 64;
#pragma unroll
        for (int ks2 = 0; ks2 < 2; ks2++) {
            bf16x8 pf = *(const bf16x8*)&ldsP[w][ks2][quad][cm][0];
            const __bf16* vr = vp + ks2 * 32 + quad * 8;
#pragma unroll
            for (int nt = 0; nt < 16; nt++) {
                bf16x8 vf = *(const bf16x8*)(vr + (nt * 16 + cm) * T_);
                accO[nt] = MFMA16(pf, vf, accO[nt]);
            }
        }
        __syncthreads();
    }

    // epilogue: store unnormalized partial + (m, l)
    const int rloc = w * 16 + quad * 4;          // local row of acc reg i
    float* op = Opart + ((size_t)pid * 64 + rloc) * HS_;
#pragma unroll
    for (int nt = 0; nt < 16; nt++)
#pragma unroll
        for (int i = 0; i < 4; i++)
            op[(size_t)i * HS_ + nt * 16 + cm] = accO[nt][i];
    if (cm == 0) {
#pragma unroll
        for (int i = 0; i < 4; i++) {
            mpart[pid * 64 + rloc + i] = mi[i];
            lpart[pid * 64 + rloc + i] = li[i];
        }
    }
}

// ---------------------------------------------------------------------------
// Kernel 3b: combine partials.  One block per (b, qblk); 256 threads.
//   thread -> 16 rows x one float4 column group.
// ---------------------------------------------------------------------------
__global__ __launch_bounds__(256) void flash_combine(const float* __restrict__ Opart,
                                                     const float* __restrict__ mpart,
                                                     const float* __restrict__ lpart,
                                                     float* __restrict__ out) {
    const int b    = blockIdx.x >> 5;
    const int qblk = blockIdx.x & 31;
    const int nc   = (qblk >> 3) + 1;
    const int pid0 = b * CHUNKS_PER_BATCH + chunk_cum(qblk);

    const int tid  = threadIdx.x;
    const int col  = (tid & 63) * 4;
    const int r0   = (tid >> 6) * 16;

    for (int rr = 0; rr < 16; rr++) {
        const int row = r0 + rr;
        float ms = -__builtin_inff();
        for (int c = 0; c < nc; c++)
            ms = fmaxf(ms, mpart[(pid0 + c) * 64 + row]);
        f32x4 acc = (f32x4){0.f, 0.f, 0.f, 0.f};
        float l = 0.f;
        for (int c = 0; c < nc; c++) {
            float sc = exp2f(mpart[(pid0 + c) * 64 + row] - ms);
            l += lpart[(pid0 + c) * 64 + row] * sc;
            f32x4 o = *(const f32x4*)(Opart + ((size_t)(pid0 + c) * 64 + row) * HS_ + col);
            acc[0] += o[0] * sc; acc[1] += o[1] * sc;
            acc[2] += o[2] * sc; acc[3] += o[3] * sc;
        }
        float inv = 1.0f / l;
        f32x4 res = (f32x4){acc[0] * inv, acc[1] * inv, acc[2] * inv, acc[3] * inv};
        *(f32x4*)(out + ((size_t)(b * T_ + qblk * 64 + row)) * HS_ + col) = res;
    }
}

// ---------------------------------------------------------------------------
extern "C" void kernel_launch(void* const* d_in, const int* in_sizes, int n_in,
                              void* d_out, int out_size, void* d_ws, size_t ws_size,
                              hipStream_t stream) {
    const float* x  = (const float*)d_in[0];
    const float* Wq = (const float*)d_in[1];
    const float* Wk = (const float*)d_in[2];
    const float* Wv = (const float*)d_in[3];
    float* out = (float*)d_out;

    char* ws = (char*)d_ws;
    // ws layout (bytes):
    //   wt_all : 3*256*768*2          = 1,179,648
    //   qb     : 8*2048*256*2         = 8,388,608
    //   kb     : 8,388,608
    //   vt     : 8,388,608
    //   Opart  : 640*64*256*4         = 41,943,040
    //   mpart  : 640*64*4             = 163,840
    //   lpart  : 163,840
    size_t off = 0;
    __bf16* wt_all = (__bf16*)(ws + off); off += 1179648;
    __bf16* qbuf   = (__bf16*)(ws + off); off += 8388608;
    __bf16* kbuf   = (__bf16*)(ws + off); off += 8388608;
    __bf16* vbuf   = (__bf16*)(ws + off); off += 8388608;
    float*  Opart  = (float*)(ws + off);  off += (size_t)NPART * 64 * HS_ * 4;
    float*  mpart  = (float*)(ws + off);  off += (size_t)NPART * 64 * 4;
    float*  lpart  = (float*)(ws + off);  off += (size_t)NPART * 64 * 4;

    float qscale = 1.4426950408889634f / sqrtf((float)C_);

    wt_kernel<<<dim3(768, 3), 256, 0, stream>>>(Wq, Wk, Wv, wt_all, qscale);
    proj_kernel<<<dim3(256, 3), 256, 0, stream>>>(x, wt_all, qbuf, kbuf, vbuf);
    flash_part<<<dim3(NPART), 256, 0, stream>>>(qbuf, kbuf, vbuf, Opart, mpart, lpart);
    flash_combine<<<dim3(256), 256, 0, stream>>>(Opart, mpart, lpart, out);
}

// Round 3
// 335.750 us; speedup vs baseline: 1.9084x; 1.4350x over previous
//
#include <hip/hip_runtime.h>
#include <hip/hip_bf16.h>
#include <math.h>

// Problem constants
#define B_  8
#define T_  2048
#define C_  768
#define HS_ 256

// Split-K flash: chunk = 8 k-tiles (512 keys). Per batch 80 chunks; 640 total.
#define CHUNK_TILES 8
#define CHUNKS_PER_BATCH 80
#define NPART (CHUNKS_PER_BATCH * B_)   // 640

typedef float  f32x4  __attribute__((ext_vector_type(4)));
typedef __bf16 bf16x8 __attribute__((ext_vector_type(8)));
typedef __bf16 bf16x4 __attribute__((ext_vector_type(4)));

#define MFMA16(a, b, c) __builtin_amdgcn_mfma_f32_16x16x32_bf16((a), (b), (c), 0, 0, 0)

// global->LDS async copy, 16B per lane (dest = wave-uniform base + lane*16)
#define GLOAD_LDS16(gp, lp)                                                     \
    __builtin_amdgcn_global_load_lds(                                           \
        (const __attribute__((address_space(1))) void*)(gp),                    \
        (__attribute__((address_space(3))) void*)(lp), 16, 0, 0)

__device__ __forceinline__ int chunk_cum(int q) {
    int g = q >> 3;
    return 4 * g * (g + 1) + (q - 8 * g) * (g + 1);
}

// ---------------------------------------------------------------------------
// Kernel 0: x fp32 -> bf16 (coalesced, 8 elem/thread)
// ---------------------------------------------------------------------------
__global__ __launch_bounds__(256) void xb_kernel(const float* __restrict__ x,
                                                 __bf16* __restrict__ xb) {
    size_t i = ((size_t)blockIdx.x * 256 + threadIdx.x) * 8;
    f32x4 a = *(const f32x4*)(x + i);
    f32x4 b = *(const f32x4*)(x + i + 4);
    bf16x8 o;
    o[0] = (__bf16)a[0]; o[1] = (__bf16)a[1]; o[2] = (__bf16)a[2]; o[3] = (__bf16)a[3];
    o[4] = (__bf16)b[0]; o[5] = (__bf16)b[1]; o[6] = (__bf16)b[2]; o[7] = (__bf16)b[3];
    *(bf16x8*)(xb + i) = o;
}

// ---------------------------------------------------------------------------
// Kernel 1: weights -> bf16, transposed to [n(768)][k(768)] (Q|K|V stacked).
// Softmax scale * log2(e) folded into Wq.
// ---------------------------------------------------------------------------
__global__ __launch_bounds__(256) void wt_kernel(const float* __restrict__ Wq,
                                                 const float* __restrict__ Wk,
                                                 const float* __restrict__ Wv,
                                                 __bf16* __restrict__ wt_all,
                                                 float qscale) {
    int idx = blockIdx.x * 256 + threadIdx.x;   // [0, 768*256)
    int mat = blockIdx.y;
    const float* W = (mat == 0) ? Wq : ((mat == 1) ? Wk : Wv);
    float scale = (mat == 0) ? qscale : 1.0f;
    int k = idx >> 8;    // 0..767
    int n = idx & 255;   // 0..255
    wt_all[((size_t)mat * HS_ + n) * C_ + k] = (__bf16)(W[idx] * scale);
}

// ---------------------------------------------------------------------------
// Kernel 2: fused QKV GEMM (m97 structure).
//   xb [16384][768] bf16, wt [768][768] bf16 -> fragment-layout q/k/v.
//   128x128 tile, BK=32, 4 waves (2x2 of 64x64), global_load_lds staging.
// Fragment layouts (element index, all *8 = 8 bf16 per lane slot):
//   Q: ((((b*32+qt)*4 + w16)*8 + ks )*64 + lane)   lane = (k>>3&3)*16 + (t&15)
//   K: ((((b*32+kt)*8 + ks )*4 + ns )*64 + lane)   lane = (k>>3&3)*16 + (t&15)
//   V: ((((b*32+kt)*2 + ks2)*16 + ntv)*64 + lane)  lane = (s>>3&3)*16 + (d&15), j = s&7
// ---------------------------------------------------------------------------
__global__ __launch_bounds__(256) void proj_kernel(const __bf16* __restrict__ xb,
                                                   const __bf16* __restrict__ wt,
                                                   __bf16* __restrict__ qf_,
                                                   __bf16* __restrict__ kf_,
                                                   __bf16* __restrict__ vf_) {
    __shared__ alignas(16) __bf16 ldsA[128 * 32];
    __shared__ alignas(16) __bf16 ldsB[128 * 32];

    const int tid  = threadIdx.x;
    const int w    = tid >> 6;
    const int lane = tid & 63;
    const int cm   = lane & 15;
    const int quad = lane >> 4;
    const int wm   = w & 1;
    const int wn   = w >> 1;
    const int m0   = blockIdx.x * 128;
    const int n0   = blockIdx.y * 128;

    f32x4 acc[4][4];
#pragma unroll
    for (int i = 0; i < 4; i++)
#pragma unroll
        for (int j = 0; j < 4; j++) acc[i][j] = (f32x4){0.f, 0.f, 0.f, 0.f};

    for (int k0 = 0; k0 < C_; k0 += 32) {
        __syncthreads();   // previous-iter LDS reads done
#pragma unroll
        for (int h = 0; h < 2; h++) {
            int c = tid + h * 256;   // 16B chunk id; row = c>>2, col granule = c&3
            GLOAD_LDS16(xb + (size_t)(m0 + (c >> 2)) * C_ + k0 + (c & 3) * 8,
                        ldsA + c * 8);
        }
#pragma unroll
        for (int h = 0; h < 2; h++) {
            int c = tid + h * 256;
            GLOAD_LDS16(wt + (size_t)(n0 + (c >> 2)) * C_ + k0 + (c & 3) * 8,
                        ldsB + c * 8);
        }
        __syncthreads();   // staging visible (drains vmcnt)

        bf16x8 af[4], bfr[4];
#pragma unroll
        for (int mt = 0; mt < 4; mt++)
            af[mt] = *(const bf16x8*)&ldsA[(wm * 64 + mt * 16 + cm) * 32 + quad * 8];
#pragma unroll
        for (int nt = 0; nt < 4; nt++)
            bfr[nt] = *(const bf16x8*)&ldsB[(wn * 64 + nt * 16 + cm) * 32 + quad * 8];
#pragma unroll
        for (int mt = 0; mt < 4; mt++)
#pragma unroll
            for (int nt = 0; nt < 4; nt++)
                acc[mt][nt] = MFMA16(af[mt], bfr[nt], acc[mt][nt]);
    }

    // ---- epilogue: write fragment layouts ----
    // rows: t = m0 + wm*64 + mt*16 + quad*4 + i ; cols: d = dBase + nt*16 + cm
    const int mat   = n0 >> 8;                 // 0=Q 1=K 2=V (128 | 256)
    const int dBase = (n0 & 255) + wn * 64;
    const int b     = m0 >> 11;
    const int rt    = ((m0 & 2047) + wm * 64) >> 6;   // q/k tile index (wave-uniform)

    if (mat == 0) {
#pragma unroll
        for (int mt = 0; mt < 4; mt++)
#pragma unroll
            for (int nt = 0; nt < 4; nt++) {
                int ksq   = (dBase >> 5) + (nt >> 1);
                int quad2 = (nt & 1) * 2 + (cm >> 3);
                int j     = cm & 7;
                size_t base = ((((size_t)(b * 32 + rt) * 4 + mt) * 8 + ksq) * 64
                               + quad2 * 16) * 8 + j;
#pragma unroll
                for (int i = 0; i < 4; i++)
                    qf_[base + (quad * 4 + i) * 8] = (__bf16)acc[mt][nt][i];
            }
    } else if (mat == 1) {
#pragma unroll
        for (int mt = 0; mt < 4; mt++)
#pragma unroll
            for (int nt = 0; nt < 4; nt++) {
                int ksq   = (dBase >> 5) + (nt >> 1);
                int quad2 = (nt & 1) * 2 + (cm >> 3);
                int j     = cm & 7;
                size_t base = ((((size_t)(b * 32 + rt) * 8 + ksq) * 4 + mt) * 64
                               + quad2 * 16) * 8 + j;
#pragma unroll
                for (int i = 0; i < 4; i++)
                    kf_[base + (quad * 4 + i) * 8] = (__bf16)acc[mt][nt][i];
            }
    } else {
#pragma unroll
        for (int mt = 0; mt < 4; mt++) {
            int ks2   = (mt >> 1) & 1;
            int quadF = (mt & 1) * 2 + (quad >> 1);
            int jb    = (quad & 1) * 4;
#pragma unroll
            for (int nt = 0; nt < 4; nt++) {
                int ntv = (dBase >> 4) + nt;
                size_t idx = ((((size_t)(b * 32 + rt) * 2 + ks2) * 16 + ntv) * 64
                              + quadF * 16 + cm) * 8 + jb;
                bf16x4 v4;
                v4[0] = (__bf16)acc[mt][nt][0]; v4[1] = (__bf16)acc[mt][nt][1];
                v4[2] = (__bf16)acc[mt][nt][2]; v4[3] = (__bf16)acc[mt][nt][3];
                *(bf16x4*)(vf_ + idx) = v4;
            }
        }
    }
}

// ---------------------------------------------------------------------------
// Kernel 3a: split-K causal flash partial — all fragment loads coalesced
// (base + lane*16B) thanks to pre-swizzled layouts.
// ---------------------------------------------------------------------------
__global__ __launch_bounds__(256) void flash_part(const __bf16* __restrict__ qf_,
                                                  const __bf16* __restrict__ kf_,
                                                  const __bf16* __restrict__ vf_,
                                                  float* __restrict__ Opart,
                                                  float* __restrict__ mpart,
                                                  float* __restrict__ lpart) {
    __shared__ __bf16 ldsP[4][2][4][16][8];

    const int tid  = threadIdx.x;
    const int w    = tid >> 6;
    const int lane = tid & 63;
    const int cm   = lane & 15;
    const int quad = lane >> 4;

    const int pid = blockIdx.x;                 // [0, 640)
    const int b   = pid / CHUNKS_PER_BATCH;
    int r = pid - b * CHUNKS_PER_BATCH;
    int qblk = 0, ci = 0;
#pragma unroll
    for (int g = 0; g < 4; g++) {
        int gs = 8 * (g + 1);
        if (r < gs) { qblk = g * 8 + r / (g + 1); ci = r % (g + 1); break; }
        r -= gs;
    }
    const int kt_begin = ci * CHUNK_TILES;
    const int kt_end   = min(kt_begin + CHUNK_TILES, qblk + 1);

    // Q fragments: coalesced
    const __bf16* qp = qf_ + (((size_t)(b * 32 + qblk) * 4 + w) * 8) * 512 + lane * 8;
    bf16x8 qf[8];
#pragma unroll
    for (int ks = 0; ks < 8; ks++) qf[ks] = *(const bf16x8*)(qp + ks * 512);

    f32x4 accO[16];
#pragma unroll
    for (int i = 0; i < 16; i++) accO[i] = (f32x4){0.f, 0.f, 0.f, 0.f};
    float mi[4], li[4];
#pragma unroll
    for (int i = 0; i < 4; i++) { mi[i] = -__builtin_inff(); li[i] = 0.f; }

    const int qg = qblk * 64 + w * 16 + quad * 4;

    for (int kt = kt_begin; kt < kt_end; kt++) {
        f32x4 s[4];
#pragma unroll
        for (int i = 0; i < 4; i++) s[i] = (f32x4){0.f, 0.f, 0.f, 0.f};
        const __bf16* kp = kf_ + ((size_t)(b * 32 + kt) * 8) * 2048 + lane * 8;
#pragma unroll
        for (int nsub = 0; nsub < 4; nsub++) {
#pragma unroll
            for (int ks = 0; ks < 8; ks++) {
                bf16x8 kfr = *(const bf16x8*)(kp + ks * 2048 + nsub * 512);
                s[nsub] = MFMA16(qf[ks], kfr, s[nsub]);
            }
        }
        if (kt == qblk) {
#pragma unroll
            for (int nsub = 0; nsub < 4; nsub++)
#pragma unroll
                for (int i = 0; i < 4; i++)
                    if (kt * 64 + nsub * 16 + cm > qg + i)
                        s[nsub][i] = -__builtin_inff();
        }
        float pm[4];
#pragma unroll
        for (int i = 0; i < 4; i++)
            pm[i] = fmaxf(fmaxf(s[0][i], s[1][i]), fmaxf(s[2][i], s[3][i]));
#pragma unroll
        for (int off = 1; off < 16; off <<= 1)
#pragma unroll
            for (int i = 0; i < 4; i++)
                pm[i] = fmaxf(pm[i], __shfl_xor(pm[i], off));

        float alpha[4], rs[4];
#pragma unroll
        for (int i = 0; i < 4; i++) {
            float mn = fmaxf(mi[i], pm[i]);
            alpha[i] = exp2f(mi[i] - mn);
            mi[i] = mn;
            rs[i] = 0.f;
        }
#pragma unroll
        for (int nsub = 0; nsub < 4; nsub++)
#pragma unroll
            for (int i = 0; i < 4; i++) {
                float p = exp2f(s[nsub][i] - mi[i]);
                rs[i] += p;
                int c = nsub * 16 + cm;
                ldsP[w][c >> 5][(c >> 3) & 3][quad * 4 + i][c & 7] = (__bf16)p;
            }
#pragma unroll
        for (int off = 1; off < 16; off <<= 1)
#pragma unroll
            for (int i = 0; i < 4; i++)
                rs[i] += __shfl_xor(rs[i], off);
#pragma unroll
        for (int i = 0; i < 4; i++) li[i] = li[i] * alpha[i] + rs[i];
#pragma unroll
        for (int nt = 0; nt < 16; nt++)
#pragma unroll
            for (int i = 0; i < 4; i++) accO[nt][i] *= alpha[i];

        __syncthreads();
        const __bf16* vp = vf_ + ((size_t)(b * 32 + kt) * 2) * 8192 + lane * 8;
#pragma unroll
        for (int ks2 = 0; ks2 < 2; ks2++) {
            bf16x8 pf = *(const bf16x8*)&ldsP[w][ks2][quad][cm][0];
#pragma unroll
            for (int nt = 0; nt < 16; nt++) {
                bf16x8 vfr = *(const bf16x8*)(vp + ks2 * 8192 + nt * 512);
                accO[nt] = MFMA16(pf, vfr, accO[nt]);
            }
        }
        __syncthreads();
    }

    const int rloc = w * 16 + quad * 4;
    float* op = Opart + ((size_t)pid * 64 + rloc) * HS_;
#pragma unroll
    for (int nt = 0; nt < 16; nt++)
#pragma unroll
        for (int i = 0; i < 4; i++)
            op[(size_t)i * HS_ + nt * 16 + cm] = accO[nt][i];
    if (cm == 0) {
#pragma unroll
        for (int i = 0; i < 4; i++) {
            mpart[pid * 64 + rloc + i] = mi[i];
            lpart[pid * 64 + rloc + i] = li[i];
        }
    }
}

// ---------------------------------------------------------------------------
// Kernel 3b: combine partials.
// ---------------------------------------------------------------------------
__global__ __launch_bounds__(256) void flash_combine(const float* __restrict__ Opart,
                                                     const float* __restrict__ mpart,
                                                     const float* __restrict__ lpart,
                                                     float* __restrict__ out) {
    const int b    = blockIdx.x >> 5;
    const int qblk = blockIdx.x & 31;
    const int nc   = (qblk >> 3) + 1;
    const int pid0 = b * CHUNKS_PER_BATCH + chunk_cum(qblk);

    const int tid  = threadIdx.x;
    const int col  = (tid & 63) * 4;
    const int r0   = (tid >> 6) * 16;

    for (int rr = 0; rr < 16; rr++) {
        const int row = r0 + rr;
        float ms = -__builtin_inff();
        for (int c = 0; c < nc; c++)
            ms = fmaxf(ms, mpart[(pid0 + c) * 64 + row]);
        f32x4 acc = (f32x4){0.f, 0.f, 0.f, 0.f};
        float l = 0.f;
        for (int c = 0; c < nc; c++) {
            float sc = exp2f(mpart[(pid0 + c) * 64 + row] - ms);
            l += lpart[(pid0 + c) * 64 + row] * sc;
            f32x4 o = *(const f32x4*)(Opart + ((size_t)(pid0 + c) * 64 + row) * HS_ + col);
            acc[0] += o[0] * sc; acc[1] += o[1] * sc;
            acc[2] += o[2] * sc; acc[3] += o[3] * sc;
        }
        float inv = 1.0f / l;
        f32x4 res = (f32x4){acc[0] * inv, acc[1] * inv, acc[2] * inv, acc[3] * inv};
        *(f32x4*)(out + ((size_t)(b * T_ + qblk * 64 + row)) * HS_ + col) = res;
    }
}

// ---------------------------------------------------------------------------
extern "C" void kernel_launch(void* const* d_in, const int* in_sizes, int n_in,
                              void* d_out, int out_size, void* d_ws, size_t ws_size,
                              hipStream_t stream) {
    const float* x  = (const float*)d_in[0];
    const float* Wq = (const float*)d_in[1];
    const float* Wk = (const float*)d_in[2];
    const float* Wv = (const float*)d_in[3];
    float* out = (float*)d_out;

    char* ws = (char*)d_ws;
    // ws layout (bytes), xb overlapped with Opart/m/l (xb dead after proj):
    //   wt_all : 768*768*2            = 1,179,648
    //   qfrag  : 8*2048*256*2         = 8,388,608
    //   kfrag  : 8,388,608
    //   vfrag  : 8,388,608
    //   union  : xb 25,165,824 | Opart 41,943,040 + mpart 163,840 + lpart 163,840
    size_t off = 0;
    __bf16* wt_all = (__bf16*)(ws + off); off += 1179648;
    __bf16* qfrag  = (__bf16*)(ws + off); off += 8388608;
    __bf16* kfrag  = (__bf16*)(ws + off); off += 8388608;
    __bf16* vfrag  = (__bf16*)(ws + off); off += 8388608;
    __bf16* xb     = (__bf16*)(ws + off);
    float*  Opart  = (float*)(ws + off);  off += (size_t)NPART * 64 * HS_ * 4;
    float*  mpart  = (float*)(ws + off);  off += (size_t)NPART * 64 * 4;
    float*  lpart  = (float*)(ws + off);

    float qscale = 1.4426950408889634f / sqrtf((float)C_);

    xb_kernel<<<dim3(6144), 256, 0, stream>>>(x, xb);
    wt_kernel<<<dim3(768, 3), 256, 0, stream>>>(Wq, Wk, Wv, wt_all, qscale);
    proj_kernel<<<dim3(128, 6), 256, 0, stream>>>(xb, wt_all, qfrag, kfrag, vfrag);
    flash_part<<<dim3(NPART), 256, 0, stream>>>(qfrag, kfrag, vfrag, Opart, mpart, lpart);
    flash_combine<<<dim3(256), 256, 0, stream>>>(Opart, mpart, lpart, out);
}

// Round 4
// 200.572 us; speedup vs baseline: 3.1946x; 1.6740x over previous
//
#include <hip/hip_runtime.h>
#include <hip/hip_bf16.h>
#include <math.h>

// Problem constants
#define B_  8
#define T_  2048
#define C_  768
#define HS_ 256

// Split-K flash: chunk = 8 k-tiles (512 keys). Per batch 80 chunks; 640 total.
#define CHUNK_TILES 8
#define CHUNKS_PER_BATCH 80
#define NPART (CHUNKS_PER_BATCH * B_)   // 640

typedef float  f32x4  __attribute__((ext_vector_type(4)));
typedef __bf16 bf16x8 __attribute__((ext_vector_type(8)));
typedef __bf16 bf16x4 __attribute__((ext_vector_type(4)));

#define MFMA16(a, b, c) __builtin_amdgcn_mfma_f32_16x16x32_bf16((a), (b), (c), 0, 0, 0)

// global->LDS async copy, 16B per lane (dest = wave-uniform base + lane*16)
#define GLOAD_LDS16(gp, lp)                                                     \
    __builtin_amdgcn_global_load_lds(                                           \
        (const __attribute__((address_space(1))) void*)(gp),                    \
        (__attribute__((address_space(3))) void*)(lp), 16, 0, 0)

__device__ __forceinline__ int chunk_cum(int q) {
    int g = q >> 3;
    return 4 * g * (g + 1) + (q - 8 * g) * (g + 1);
}

// ---------------------------------------------------------------------------
// Kernel 0: x fp32 -> bf16 (coalesced, 8 elem/thread)
// ---------------------------------------------------------------------------
__global__ __launch_bounds__(256) void xb_kernel(const float* __restrict__ x,
                                                 __bf16* __restrict__ xb) {
    size_t i = ((size_t)blockIdx.x * 256 + threadIdx.x) * 8;
    f32x4 a = *(const f32x4*)(x + i);
    f32x4 b = *(const f32x4*)(x + i + 4);
    bf16x8 o;
    o[0] = (__bf16)a[0]; o[1] = (__bf16)a[1]; o[2] = (__bf16)a[2]; o[3] = (__bf16)a[3];
    o[4] = (__bf16)b[0]; o[5] = (__bf16)b[1]; o[6] = (__bf16)b[2]; o[7] = (__bf16)b[3];
    *(bf16x8*)(xb + i) = o;
}

// ---------------------------------------------------------------------------
// Kernel 1: weights -> bf16, transposed to [n(768)][k(768)] (Q|K|V stacked).
// Softmax scale * log2(e) folded into Wq.
// ---------------------------------------------------------------------------
__global__ __launch_bounds__(256) void wt_kernel(const float* __restrict__ Wq,
                                                 const float* __restrict__ Wk,
                                                 const float* __restrict__ Wv,
                                                 __bf16* __restrict__ wt_all,
                                                 float qscale) {
    int idx = blockIdx.x * 256 + threadIdx.x;   // [0, 768*256)
    int mat = blockIdx.y;
    const float* W = (mat == 0) ? Wq : ((mat == 1) ? Wk : Wv);
    float scale = (mat == 0) ? qscale : 1.0f;
    int k = idx >> 8;    // 0..767
    int n = idx & 255;   // 0..255
    wt_all[((size_t)mat * HS_ + n) * C_ + k] = (__bf16)(W[idx] * scale);
}

// ---------------------------------------------------------------------------
// Kernel 2: fused QKV GEMM (m97 structure) -> fragment-layout q/k/v.
// Fragment layouts (element index, all *8 = 8 bf16 per lane slot):
//   Q: ((((b*32+qt)*4 + w16)*8 + ks )*64 + lane)
//   K: ((((b*32+kt)*8 + ks )*4 + ns )*64 + lane)
//   V: ((((b*32+kt)*2 + ks2)*16 + ntv)*64 + lane)
// ---------------------------------------------------------------------------
__global__ __launch_bounds__(256) void proj_kernel(const __bf16* __restrict__ xb,
                                                   const __bf16* __restrict__ wt,
                                                   __bf16* __restrict__ qf_,
                                                   __bf16* __restrict__ kf_,
                                                   __bf16* __restrict__ vf_) {
    __shared__ alignas(16) __bf16 ldsA[128 * 32];
    __shared__ alignas(16) __bf16 ldsB[128 * 32];

    const int tid  = threadIdx.x;
    const int w    = tid >> 6;
    const int lane = tid & 63;
    const int cm   = lane & 15;
    const int quad = lane >> 4;
    const int wm   = w & 1;
    const int wn   = w >> 1;
    const int m0   = blockIdx.x * 128;
    const int n0   = blockIdx.y * 128;

    f32x4 acc[4][4];
#pragma unroll
    for (int i = 0; i < 4; i++)
#pragma unroll
        for (int j = 0; j < 4; j++) acc[i][j] = (f32x4){0.f, 0.f, 0.f, 0.f};

    for (int k0 = 0; k0 < C_; k0 += 32) {
        __syncthreads();
#pragma unroll
        for (int h = 0; h < 2; h++) {
            int c = tid + h * 256;
            GLOAD_LDS16(xb + (size_t)(m0 + (c >> 2)) * C_ + k0 + (c & 3) * 8,
                        ldsA + c * 8);
        }
#pragma unroll
        for (int h = 0; h < 2; h++) {
            int c = tid + h * 256;
            GLOAD_LDS16(wt + (size_t)(n0 + (c >> 2)) * C_ + k0 + (c & 3) * 8,
                        ldsB + c * 8);
        }
        __syncthreads();

        bf16x8 af[4], bfr[4];
#pragma unroll
        for (int mt = 0; mt < 4; mt++)
            af[mt] = *(const bf16x8*)&ldsA[(wm * 64 + mt * 16 + cm) * 32 + quad * 8];
#pragma unroll
        for (int nt = 0; nt < 4; nt++)
            bfr[nt] = *(const bf16x8*)&ldsB[(wn * 64 + nt * 16 + cm) * 32 + quad * 8];
#pragma unroll
        for (int mt = 0; mt < 4; mt++)
#pragma unroll
            for (int nt = 0; nt < 4; nt++)
                acc[mt][nt] = MFMA16(af[mt], bfr[nt], acc[mt][nt]);
    }

    const int mat   = n0 >> 8;                 // 0=Q 1=K 2=V
    const int dBase = (n0 & 255) + wn * 64;
    const int b     = m0 >> 11;
    const int rt    = ((m0 & 2047) + wm * 64) >> 6;

    if (mat == 0) {
#pragma unroll
        for (int mt = 0; mt < 4; mt++)
#pragma unroll
            for (int nt = 0; nt < 4; nt++) {
                int ksq   = (dBase >> 5) + (nt >> 1);
                int quad2 = (nt & 1) * 2 + (cm >> 3);
                int j     = cm & 7;
                size_t base = ((((size_t)(b * 32 + rt) * 4 + mt) * 8 + ksq) * 64
                               + quad2 * 16) * 8 + j;
#pragma unroll
                for (int i = 0; i < 4; i++)
                    qf_[base + (quad * 4 + i) * 8] = (__bf16)acc[mt][nt][i];
            }
    } else if (mat == 1) {
#pragma unroll
        for (int mt = 0; mt < 4; mt++)
#pragma unroll
            for (int nt = 0; nt < 4; nt++) {
                int ksq   = (dBase >> 5) + (nt >> 1);
                int quad2 = (nt & 1) * 2 + (cm >> 3);
                int j     = cm & 7;
                size_t base = ((((size_t)(b * 32 + rt) * 8 + ksq) * 4 + mt) * 64
                               + quad2 * 16) * 8 + j;
#pragma unroll
                for (int i = 0; i < 4; i++)
                    kf_[base + (quad * 4 + i) * 8] = (__bf16)acc[mt][nt][i];
            }
    } else {
#pragma unroll
        for (int mt = 0; mt < 4; mt++) {
            int ks2   = (mt >> 1) & 1;
            int quadF = (mt & 1) * 2 + (quad >> 1);
            int jb    = (quad & 1) * 4;
#pragma unroll
            for (int nt = 0; nt < 4; nt++) {
                int ntv = (dBase >> 4) + nt;
                size_t idx = ((((size_t)(b * 32 + rt) * 2 + ks2) * 16 + ntv) * 64
                              + quadF * 16 + cm) * 8 + jb;
                bf16x4 v4;
                v4[0] = (__bf16)acc[mt][nt][0]; v4[1] = (__bf16)acc[mt][nt][1];
                v4[2] = (__bf16)acc[mt][nt][2]; v4[3] = (__bf16)acc[mt][nt][3];
                *(bf16x4*)(vf_ + idx) = v4;
            }
        }
    }
}

// ---------------------------------------------------------------------------
// Kernel 3a: split-K causal flash partial.
//   K/V tiles staged ONCE per block into LDS via global_load_lds (async,
//   no VGPR cost); all 4 waves read fragments from LDS (ds_read_b128).
//   P buffer aliases the consumed K region (3rd barrier protects).
//   Heavy chunks first (r reversed); batch = pid&7 for L2/XCD locality.
// ---------------------------------------------------------------------------
__global__ __launch_bounds__(256) void flash_part(const __bf16* __restrict__ qf_,
                                                  const __bf16* __restrict__ kf_,
                                                  const __bf16* __restrict__ vf_,
                                                  float* __restrict__ Opart,
                                                  float* __restrict__ mpart,
                                                  float* __restrict__ lpart) {
    __shared__ alignas(16) __bf16 ldsK[8 * 4 * 64 * 8];   // 32 KB (P aliases head)
    __shared__ alignas(16) __bf16 ldsV[2 * 16 * 64 * 8];  // 32 KB

    const int tid  = threadIdx.x;
    const int w    = tid >> 6;
    const int lane = tid & 63;
    const int cm   = lane & 15;
    const int quad = lane >> 4;

    const int pid = blockIdx.x;                 // [0, 640)
    const int b   = pid & 7;                    // batch -> XCD locality
    int r = (CHUNKS_PER_BATCH - 1) - (pid >> 3);  // heavy chunks first
    int qblk = 0, ci = 0;
    {
        int rr = r;
#pragma unroll
        for (int g = 0; g < 4; g++) {
            int gs = 8 * (g + 1);
            if (rr < gs) { qblk = g * 8 + rr / (g + 1); ci = rr % (g + 1); break; }
            rr -= gs;
        }
    }
    const int lpid = b * CHUNKS_PER_BATCH + r;  // logical output slot
    const int kt_begin = ci * CHUNK_TILES;
    const int kt_end   = min(kt_begin + CHUNK_TILES, qblk + 1);

    // Q fragments: coalesced (base + lane*16B)
    const __bf16* qp = qf_ + (((size_t)(b * 32 + qblk) * 4 + w) * 8) * 512 + lane * 8;
    bf16x8 qf[8];
#pragma unroll
    for (int ks = 0; ks < 8; ks++) qf[ks] = *(const bf16x8*)(qp + ks * 512);

    f32x4 accO[16];
#pragma unroll
    for (int i = 0; i < 16; i++) accO[i] = (f32x4){0.f, 0.f, 0.f, 0.f};
    float mi[4], li[4];
#pragma unroll
    for (int i = 0; i < 4; i++) { mi[i] = -__builtin_inff(); li[i] = 0.f; }

    const int qg = qblk * 64 + w * 16 + quad * 4;

    for (int kt = kt_begin; kt < kt_end; kt++) {
        __syncthreads();   // (A) prior tile's LDS fully consumed by all waves

        // ---- stage K (32 KB) + V (32 KB) tiles into LDS, async ----
        const __bf16* kg = kf_ + ((size_t)(b * 32 + kt) * 8) * 2048;
        const __bf16* vg = vf_ + ((size_t)(b * 32 + kt) * 2) * 8192;
#pragma unroll
        for (int h = 0; h < 8; h++) {
            GLOAD_LDS16(kg + (h * 256 + tid) * 8, ldsK + (h * 256 + w * 64) * 8);
            GLOAD_LDS16(vg + (h * 256 + tid) * 8, ldsV + (h * 256 + w * 64) * 8);
        }
        __syncthreads();   // (B) vmcnt drained -> K/V visible

        // ---- S = Q K^T (16 x 64 per wave) ----
        f32x4 s[4];
#pragma unroll
        for (int i = 0; i < 4; i++) s[i] = (f32x4){0.f, 0.f, 0.f, 0.f};
#pragma unroll
        for (int nsub = 0; nsub < 4; nsub++) {
#pragma unroll
            for (int ks = 0; ks < 8; ks++) {
                bf16x8 kfr = *(const bf16x8*)&ldsK[ks * 2048 + nsub * 512 + lane * 8];
                s[nsub] = MFMA16(qf[ks], kfr, s[nsub]);
            }
        }
        if (kt == qblk) {
#pragma unroll
            for (int nsub = 0; nsub < 4; nsub++)
#pragma unroll
                for (int i = 0; i < 4; i++)
                    if (kt * 64 + nsub * 16 + cm > qg + i)
                        s[nsub][i] = -__builtin_inff();
        }
        // ---- online softmax ----
        float pm[4];
#pragma unroll
        for (int i = 0; i < 4; i++)
            pm[i] = fmaxf(fmaxf(s[0][i], s[1][i]), fmaxf(s[2][i], s[3][i]));
#pragma unroll
        for (int off = 1; off < 16; off <<= 1)
#pragma unroll
            for (int i = 0; i < 4; i++)
                pm[i] = fmaxf(pm[i], __shfl_xor(pm[i], off));

        float alpha[4], rs[4], p[4][4];
#pragma unroll
        for (int i = 0; i < 4; i++) {
            float mn = fmaxf(mi[i], pm[i]);
            alpha[i] = exp2f(mi[i] - mn);
            mi[i] = mn;
            rs[i] = 0.f;
        }
#pragma unroll
        for (int nsub = 0; nsub < 4; nsub++)
#pragma unroll
            for (int i = 0; i < 4; i++) {
                p[nsub][i] = exp2f(s[nsub][i] - mi[i]);
                rs[i] += p[nsub][i];
            }
#pragma unroll
        for (int off = 1; off < 16; off <<= 1)
#pragma unroll
            for (int i = 0; i < 4; i++)
                rs[i] += __shfl_xor(rs[i], off);
#pragma unroll
        for (int i = 0; i < 4; i++) li[i] = li[i] * alpha[i] + rs[i];
#pragma unroll
        for (int nt = 0; nt < 16; nt++)
#pragma unroll
            for (int i = 0; i < 4; i++) accO[nt][i] *= alpha[i];

        __syncthreads();   // (C) all waves done reading ldsK -> safe to alias P

        // ---- P -> per-wave LDS slice (aliases ldsK head), A-frag order ----
        __bf16* ldsP = ldsK + w * 1024;
#pragma unroll
        for (int nsub = 0; nsub < 4; nsub++)
#pragma unroll
            for (int i = 0; i < 4; i++) {
                int c = nsub * 16 + cm;
                ldsP[(c >> 5) * 512 + ((c >> 3) & 3) * 128 + (quad * 4 + i) * 8 + (c & 7)]
                    = (__bf16)p[nsub][i];
            }
        // ---- O += P V ----
#pragma unroll
        for (int ks2 = 0; ks2 < 2; ks2++) {
            bf16x8 pf = *(const bf16x8*)&ldsP[ks2 * 512 + quad * 128 + cm * 8];
#pragma unroll
            for (int nt = 0; nt < 16; nt++) {
                bf16x8 vfr = *(const bf16x8*)&ldsV[ks2 * 8192 + nt * 512 + lane * 8];
                accO[nt] = MFMA16(pf, vfr, accO[nt]);
            }
        }
    }

    const int rloc = w * 16 + quad * 4;
    float* op = Opart + ((size_t)lpid * 64 + rloc) * HS_;
#pragma unroll
    for (int nt = 0; nt < 16; nt++)
#pragma unroll
        for (int i = 0; i < 4; i++)
            op[(size_t)i * HS_ + nt * 16 + cm] = accO[nt][i];
    if (cm == 0) {
#pragma unroll
        for (int i = 0; i < 4; i++) {
            mpart[lpid * 64 + rloc + i] = mi[i];
            lpart[lpid * 64 + rloc + i] = li[i];
        }
    }
}

// ---------------------------------------------------------------------------
// Kernel 3b: combine partials.  Grid (256, 4): 16 rows per block-y.
// ---------------------------------------------------------------------------
__global__ __launch_bounds__(256) void flash_combine(const float* __restrict__ Opart,
                                                     const float* __restrict__ mpart,
                                                     const float* __restrict__ lpart,
                                                     float* __restrict__ out) {
    const int b    = blockIdx.x >> 5;
    const int qblk = blockIdx.x & 31;
    const int nc   = (qblk >> 3) + 1;
    const int pid0 = b * CHUNKS_PER_BATCH + chunk_cum(qblk);

    const int tid  = threadIdx.x;
    const int col  = (tid & 63) * 4;
    const int r0   = blockIdx.y * 16 + (tid >> 6) * 4;

    for (int rr = 0; rr < 4; rr++) {
        const int row = r0 + rr;
        float ms = -__builtin_inff();
        for (int c = 0; c < nc; c++)
            ms = fmaxf(ms, mpart[(pid0 + c) * 64 + row]);
        f32x4 acc = (f32x4){0.f, 0.f, 0.f, 0.f};
        float l = 0.f;
        for (int c = 0; c < nc; c++) {
            float sc = exp2f(mpart[(pid0 + c) * 64 + row] - ms);
            l += lpart[(pid0 + c) * 64 + row] * sc;
            f32x4 o = *(const f32x4*)(Opart + ((size_t)(pid0 + c) * 64 + row) * HS_ + col);
            acc[0] += o[0] * sc; acc[1] += o[1] * sc;
            acc[2] += o[2] * sc; acc[3] += o[3] * sc;
        }
        float inv = 1.0f / l;
        f32x4 res = (f32x4){acc[0] * inv, acc[1] * inv, acc[2] * inv, acc[3] * inv};
        *(f32x4*)(out + ((size_t)(b * T_ + qblk * 64 + row)) * HS_ + col) = res;
    }
}

// ---------------------------------------------------------------------------
extern "C" void kernel_launch(void* const* d_in, const int* in_sizes, int n_in,
                              void* d_out, int out_size, void* d_ws, size_t ws_size,
                              hipStream_t stream) {
    const float* x  = (const float*)d_in[0];
    const float* Wq = (const float*)d_in[1];
    const float* Wk = (const float*)d_in[2];
    const float* Wv = (const float*)d_in[3];
    float* out = (float*)d_out;

    char* ws = (char*)d_ws;
    size_t off = 0;
    __bf16* wt_all = (__bf16*)(ws + off); off += 1179648;
    __bf16* qfrag  = (__bf16*)(ws + off); off += 8388608;
    __bf16* kfrag  = (__bf16*)(ws + off); off += 8388608;
    __bf16* vfrag  = (__bf16*)(ws + off); off += 8388608;
    __bf16* xb     = (__bf16*)(ws + off);              // union with Opart
    float*  Opart  = (float*)(ws + off);  off += (size_t)NPART * 64 * HS_ * 4;
    float*  mpart  = (float*)(ws + off);  off += (size_t)NPART * 64 * 4;
    float*  lpart  = (float*)(ws + off);

    float qscale = 1.4426950408889634f / sqrtf((float)C_);

    xb_kernel<<<dim3(6144), 256, 0, stream>>>(x, xb);
    wt_kernel<<<dim3(768, 3), 256, 0, stream>>>(Wq, Wk, Wv, wt_all, qscale);
    proj_kernel<<<dim3(128, 6), 256, 0, stream>>>(xb, wt_all, qfrag, kfrag, vfrag);
    flash_part<<<dim3(NPART), 256, 0, stream>>>(qfrag, kfrag, vfrag, Opart, mpart, lpart);
    flash_combine<<<dim3(256, 4), 256, 0, stream>>>(Opart, mpart, lpart, out);
}